// Round 9
// baseline (276.649 us; speedup 1.0000x reference)
//
#include <hip/hip_runtime.h>

// OctVolSynth: element-wise over 256^3 volume.
//   scaling = lut[label]; v = scaling*texture; v = (v==0) ? 1 : v;
//   out0 = parenchyma * v;  out1 = (label != 0) ? 1.0f : 0.0f
//
// Session: 16B/lane shapes (R1-R9: forced MLP, nt, persistent pipelines) all
// ~99us / 3.24 TB/s. R10 scalar 4B/lane, 1 elem/thread, compiler-scheduled =
// 88-91us / 3.77 TB/s (base). R11 grid-stride regressed (2nd variable);
// R12 asm-forced depth regressed (occupancy 56%); R13 sc0/sc1/nt stores null.
// Wave math on R10: 87ns/wave/CU retirement, 2.8us lifetime, of which ~0.9us
// is the per-block LUT phase (302 loads + barrier) serving only 1 elem/thread
// -- worst amortization of the session, and every better-amortized round was
// confounded (16B width, grid-stride, or asm occupancy loss). R14 = the
// never-run combination: R10's winning scheduling/width + R12's contiguous
// 4-elem/thread layout. BLOCK=1024, CHUNKS=4, block owns 16KiB/stream
// contiguous, plain C, no asm, LUT amortized 4x.
// Predict: 78-84us, occupancy >=75%, FETCH/WRITE unchanged; null => declare
// structural ceiling next round.

#define N_ELEMS (256 * 256 * 256)
#define LUT_SIZE 302
#define BLOCK 1024
#define CHUNKS 4    // elements per thread, stride BLOCK within the block window

__global__ __launch_bounds__(BLOCK) void octvolsynth_r14(
    const int* __restrict__ labels,
    const float* __restrict__ parenchyma,
    const float* __restrict__ texture,
    const float* __restrict__ lut,
    float* __restrict__ out)
{
    __shared__ float s_lut[LUT_SIZE];
    for (int i = threadIdx.x; i < LUT_SIZE; i += BLOCK) s_lut[i] = lut[i];
    __syncthreads();

    const int base = blockIdx.x * (BLOCK * CHUNKS) + threadIdx.x;
    float* __restrict__ outm = out + N_ELEMS;

#pragma unroll
    for (int c = 0; c < CHUNKS; ++c) {
        const int i = base + c * BLOCK;

        const int   l = labels[i];
        const float p = parenchyma[i];
        const float x = texture[i];

        float v = s_lut[l] * x;
        v = (v == 0.0f) ? 1.0f : v;

        out[i]  = p * v;
        outm[i] = (l != 0) ? 1.0f : 0.0f;
    }
}

extern "C" void kernel_launch(void* const* d_in, const int* in_sizes, int n_in,
                              void* d_out, int out_size, void* d_ws, size_t ws_size,
                              hipStream_t stream) {
    const int*   labels     = (const int*)d_in[0];
    const float* parenchyma = (const float*)d_in[1];
    const float* texture    = (const float*)d_in[2];
    const float* lut        = (const float*)d_in[3];
    float* out = (float*)d_out;

    const int grid = N_ELEMS / (BLOCK * CHUNKS);   // 4096 blocks, no tail
    octvolsynth_r14<<<grid, BLOCK, 0, stream>>>(labels, parenchyma, texture, lut, out);
}

// Round 10
// 269.973 us; speedup vs baseline: 1.0247x; 1.0247x over previous
//
#include <hip/hip_runtime.h>

// OctVolSynth: element-wise over 256^3 volume.
//   scaling = lut[label]; v = scaling*texture; v = (v==0) ? 1 : v;
//   out0 = parenchyma * v;  out1 = (label != 0) ? 1.0f : 0.0f
//
// Session: R1-R9 (16B/lane, forced MLP, nt, persistent) ~99us. R10 scalar
// 4B/lane 1-elem/thread = 88-91us (base). R11 grid-stride, R12 asm depth,
// R13 sc0/sc1/nt, R14 4-elem blocking: all null/regressed. Invariant:
// duration tracks occupancy inversely; every added per-thread structure
// loses. One apparatus survived all 14 rounds untouched: the per-block LDS
// LUT stage (302-elem global read by threads 0-301, __syncthreads, LDS
// gathers, 1.16M conflict cycles/dispatch) -- paid 16384x in R10's shape,
// ~0.9us of a 2.8us wave lifetime, and the barrier couples 16 waves with
// only 2 blocks/CU of overlap. R15 deletes it: lut[l] gathered directly
// from global (1.2 KiB = 19 cache lines, L1/L2-hot). No LDS, no barrier,
// no idle-thread phase; waves fully decoupled. Single variable vs R10.
// Predict: 76-84us, occupancy >=80, LDS conflicts ->0; null => structural
// ceiling, declare next round.

#define N_ELEMS (256 * 256 * 256)
#define BLOCK 1024

__global__ __launch_bounds__(BLOCK) void octvolsynth_r15(
    const int* __restrict__ labels,
    const float* __restrict__ parenchyma,
    const float* __restrict__ texture,
    const float* __restrict__ lut,
    float* __restrict__ out)
{
    const int i = blockIdx.x * BLOCK + threadIdx.x;   // one element per thread

    const int   l = labels[i];
    const float p = parenchyma[i];
    const float x = texture[i];
    const float s = lut[l];          // direct global gather, L1/L2-hot

    float v = s * x;
    v = (v == 0.0f) ? 1.0f : v;

    out[i]           = p * v;
    out[N_ELEMS + i] = (l != 0) ? 1.0f : 0.0f;
}

extern "C" void kernel_launch(void* const* d_in, const int* in_sizes, int n_in,
                              void* d_out, int out_size, void* d_ws, size_t ws_size,
                              hipStream_t stream) {
    const int*   labels     = (const int*)d_in[0];
    const float* parenchyma = (const float*)d_in[1];
    const float* texture    = (const float*)d_in[2];
    const float* lut        = (const float*)d_in[3];
    float* out = (float*)d_out;

    const int grid = N_ELEMS / BLOCK;   // 16384 blocks, no tail
    octvolsynth_r15<<<grid, BLOCK, 0, stream>>>(labels, parenchyma, texture, lut, out);
}